// Round 1
// baseline (662.007 us; speedup 1.0000x reference)
//
#include <hip/hip_runtime.h>
#include <hip/hip_bf16.h>

// Problem constants (B=4, C=256, H=W=64, hs=ws=32, rate=2, vk=4, pad=1)
#define BB 4
#define CC 256
#define HH 64
#define WW 64
#define QRN 1024          // hs*ws = 32*32 query positions
#define KN  1024          // mn key positions
#define NN  4096          // 16 (u,v) * 256 channels

#define TILE_M 64
#define TILE_N 64
#define TILE_K 16

// ---------------------------------------------------------------------------
// out = ori_x  (fold contributions are atomically added on top)
__global__ void copy_kernel(const float* __restrict__ src,
                            float* __restrict__ dst, int n4) {
    int i = blockIdx.x * blockDim.x + threadIdx.x;
    if (i < n4)
        reinterpret_cast<float4*>(dst)[i] =
            reinterpret_cast<const float4*>(src)[i];
}

// ---------------------------------------------------------------------------
// xT[b][h][w][c] = x[b][c][h][w]   (channel-last so GEMM B-tiles coalesce)
__global__ void transpose_kernel(const float* __restrict__ x,
                                 float* __restrict__ xT) {
    __shared__ float tile[32][33];
    int bh = blockIdx.z;            // b*64 + h
    int b = bh >> 6, h = bh & 63;
    int c0 = blockIdx.y * 32, w0 = blockIdx.x * 32;

    int tw = threadIdx.x & 31;      // w offset (coalesced read)
    int tc = threadIdx.x >> 5;      // c sub-row
    #pragma unroll
    for (int i = 0; i < 4; ++i) {
        int c = tc + i * 8;
        tile[c][tw] = x[(((size_t)b * CC + c0 + c) * HH + h) * WW + w0 + tw];
    }
    __syncthreads();
    int tcw = threadIdx.x & 31;     // c offset (coalesced write)
    int twr = threadIdx.x >> 5;
    #pragma unroll
    for (int i = 0; i < 4; ++i) {
        int w = twr + i * 8;
        xT[(((size_t)b * HH + h) * WW + w0 + w) * CC + c0 + tcw] = tile[tcw][w];
    }
}

// ---------------------------------------------------------------------------
// Per-b GEMM:  P[m=QR][n'=uv*256+c] = sum_k scores[b][m][k] * V[k][n']
//   V[k][n'] = xT[b][clamp(2*(k>>5)+u-1)][clamp(2*(k&31)+v-1)][c]
// Epilogue: atomicAdd(out[b][c][2Q+u-1][2R+v-1], P * alpha/4) with crop check.
__global__ __launch_bounds__(256)
void pgemm_scatter(const float* __restrict__ scores,  // [B][1024][1024]
                   const float* __restrict__ xT,      // [B][64][64][256]
                   const float* __restrict__ x,       // [B][256][64][64] (fallback)
                   const float* __restrict__ alpha,
                   float* __restrict__ out,           // [B][256][64][64]
                   int use_xt) {
    __shared__ float As[TILE_K][TILE_M];   // k-major: inner reads are b128
    __shared__ float Bs[TILE_K][TILE_N];

    const int b      = blockIdx.z;
    const int tile_n = blockIdx.x;          // 0..63
    const int m0     = blockIdx.y * TILE_M; // QR base
    const int uv     = tile_n >> 2;         // fixed (u,v) for the whole tile
    const int u      = uv >> 2, v = uv & 3;
    const int c0     = (tile_n & 3) * 64;   // channel base

    const int t  = threadIdx.x;
    const int tx = t & 15;                  // n sub-tile (4 cols)
    const int ty = t >> 4;                  // m sub-tile (4 rows)

    float acc[4][4] = {};
    const float* sb = scores + (size_t)b * QRN * KN;

    for (int k0 = 0; k0 < KN; k0 += TILE_K) {
        // ---- stage A: 64 (m) x 16 (k); thread: row t>>2, float4 at (t&3)*4
        {
            int mr = t >> 2;
            int kc = (t & 3) * 4;
            float4 av = *reinterpret_cast<const float4*>(
                sb + (size_t)(m0 + mr) * KN + k0 + kc);
            As[kc + 0][mr] = av.x;
            As[kc + 1][mr] = av.y;
            As[kc + 2][mr] = av.z;
            As[kc + 3][mr] = av.w;
        }
        // ---- stage B: 16 (k) x 64 (c); thread: k-row t>>4, float4 at (t&15)*4
        {
            int kr = t >> 4;
            int kg = k0 + kr;
            int m  = kg >> 5, n = kg & 31;
            int rr = 2 * m + u - 1; rr = min(max(rr, 0), HH - 1);
            int cc = 2 * n + v - 1; cc = min(max(cc, 0), WW - 1);
            int ccol = (t & 15) * 4;
            if (use_xt) {
                float4 bv = *reinterpret_cast<const float4*>(
                    xT + ((((size_t)b * HH + rr) * WW + cc) * CC) + c0 + ccol);
                Bs[kr][ccol + 0] = bv.x;
                Bs[kr][ccol + 1] = bv.y;
                Bs[kr][ccol + 2] = bv.z;
                Bs[kr][ccol + 3] = bv.w;
            } else {
                #pragma unroll
                for (int j = 0; j < 4; ++j) {
                    int c = c0 + ccol + j;
                    Bs[kr][ccol + j] =
                        x[(((size_t)b * CC + c) * HH + rr) * WW + cc];
                }
            }
        }
        __syncthreads();

        #pragma unroll
        for (int k = 0; k < TILE_K; ++k) {
            float a4[4], b4[4];
            *reinterpret_cast<float4*>(a4) =
                *reinterpret_cast<const float4*>(&As[k][ty * 4]);
            *reinterpret_cast<float4*>(b4) =
                *reinterpret_cast<const float4*>(&Bs[k][tx * 4]);
            #pragma unroll
            for (int i = 0; i < 4; ++i)
                #pragma unroll
                for (int j = 0; j < 4; ++j)
                    acc[i][j] += a4[i] * b4[j];
        }
        __syncthreads();
    }

    const float scale = alpha[0] * 0.25f;
    #pragma unroll
    for (int i = 0; i < 4; ++i) {
        int qr = m0 + ty * 4 + i;
        int Q = qr >> 5, R = qr & 31;
        int h = 2 * Q + u - 1;
        int w = 2 * R + v - 1;
        if (h < 0 || h >= HH || w < 0 || w >= WW) continue;
        #pragma unroll
        for (int j = 0; j < 4; ++j) {
            int c = c0 + tx * 4 + j;
            atomicAdd(&out[(((size_t)b * CC + c) * HH + h) * WW + w],
                      acc[i][j] * scale);
        }
    }
}

// ---------------------------------------------------------------------------
extern "C" void kernel_launch(void* const* d_in, const int* in_sizes, int n_in,
                              void* d_out, int out_size, void* d_ws,
                              size_t ws_size, hipStream_t stream) {
    const float* ori_x  = (const float*)d_in[0];  // [4][256][64][64]
    const float* scores = (const float*)d_in[1];  // [4][1024][1024]
    const float* alpha  = (const float*)d_in[2];  // [1]
    float* out = (float*)d_out;
    float* xT  = (float*)d_ws;

    const size_t xt_bytes = (size_t)BB * HH * WW * CC * sizeof(float);
    const int use_xt = (ws_size >= xt_bytes) ? 1 : 0;

    // out = ori_x
    copy_kernel<<<(BB * CC * HH * WW / 4 + 255) / 256, 256, 0, stream>>>(
        ori_x, out, BB * CC * HH * WW / 4);

    // channel-last transpose into workspace
    if (use_xt)
        transpose_kernel<<<dim3(WW / 32, CC / 32, BB * HH), 256, 0, stream>>>(
            ori_x, xT);

    // GEMM + fold scatter
    pgemm_scatter<<<dim3(NN / TILE_N, QRN / TILE_M, BB), 256, 0, stream>>>(
        scores, xT, ori_x, alpha, out, use_xt);
}

// Round 2
// 95.820 us; speedup vs baseline: 6.9089x; 6.9089x over previous
//
#include <hip/hip_runtime.h>
#include <hip/hip_bf16.h>
#include <hip/hip_fp16.h>

// Problem constants (B=4, C=256, H=W=64, hs=ws=32, rate=2, vk=4, pad=1)
#define BB 4
#define CC 256
#define HH 64
#define WW 64
#define QRN 1024
#define KN  1024
#define NN  4096
#define KDIM 1120            // 33*33 = 1089 padded to 35*32
#define MROWS 1024           // pixels per parity class

typedef _Float16 f16x8 __attribute__((ext_vector_type(8)));
typedef float f32x4 __attribute__((ext_vector_type(4)));

#define AP_ELEMS ((size_t)16 * MROWS * KDIM)   // 18,350,080 halves
#define BP_ELEMS ((size_t)16 * CC * KDIM)      //  4,587,520 halves

// ===========================================================================
// FAST PATH
// ===========================================================================

// Combined scores: Ap[bc][row=hh*32+ww][k=m'*33+n'] =
//   sum_{dq,dr} s[b][(Qa-dq)*32+(Ra-dr)][(m'-dq)*32+(n'-dr)]  (masked)
// with Qa = hh+ph, Ra = ww+pw  (class = ph*2+pw; pixel h=2hh+ph, w=2ww+pw)
__global__ __launch_bounds__(256)
void build_A(const float* __restrict__ s, _Float16* __restrict__ Ap) {
    int k = blockIdx.x * 256 + threadIdx.x;        // gridDim.x = 5
    if (k >= KDIM) return;
    int rowg = blockIdx.y;                          // bc*1024 + row
    int bc = rowg >> 10, row = rowg & 1023;
    int b = bc >> 2, cls = bc & 3;
    int ph = cls >> 1, pw = cls & 1;
    int hh = row >> 5, ww = row & 31;
    int mp = (k * 993) >> 15;                       // k/33 (exact for k<2048)
    int np = k - 33 * mp;
    int Qa = hh + ph, Ra = ww + pw;
    const float* sb = s + (size_t)b * QRN * KN;
    float val = 0.f;
    #pragma unroll
    for (int dq = 0; dq < 2; ++dq) {
        int Q = Qa - dq, m = mp - dq;
        if ((unsigned)Q < 32u && (unsigned)m < 32u) {
            #pragma unroll
            for (int dr = 0; dr < 2; ++dr) {
                int R = Ra - dr, n = np - dr;
                if ((unsigned)R < 32u && (unsigned)n < 32u)
                    val += sb[(size_t)((Q << 5) + R) * KN + (m << 5) + n];
            }
        }
    }
    Ap[((size_t)bc * MROWS + row) * KDIM + k] = (_Float16)val;
}

// Gathered x samples: Bp[bc][c][k] = x[b][c][clamp(2m'+ua-1)][clamp(2n'+va-1)]
// ua = 1-ph, va = 1-pw.
__global__ __launch_bounds__(256)
void build_B(const float* __restrict__ x, _Float16* __restrict__ Bp) {
    int k = blockIdx.x * 256 + threadIdx.x;        // gridDim.x = 5
    if (k >= KDIM) return;
    int rowg = blockIdx.y;                          // bc*256 + c
    int bc = rowg >> 8, c = rowg & 255;
    int b = bc >> 2, cls = bc & 3;
    int ph = cls >> 1, pw = cls & 1;
    int ua = 1 - ph, va = 1 - pw;
    int mp = (k * 993) >> 15;
    int np = k - 33 * mp;
    int rr = 2 * mp + ua - 1; rr = min(max(rr, 0), HH - 1);
    int cc2 = 2 * np + va - 1; cc2 = min(max(cc2, 0), WW - 1);
    Bp[((size_t)bc * CC + c) * KDIM + k] =
        (_Float16)x[(((size_t)b * CC + c) * HH + rr) * WW + cc2];
}

// GEMM per (b,class): D[c][px] = sum_k Bp[c][k] * Ap[px][k]
// Tile: 64 c (M) x 128 px (N), K-chunks of 32, mfma_f32_16x16x32_f16.
// Epilogue: out[b][c][h][w] = ori_x + 0.25*alpha*D  (each pixel exactly once)
__global__ __launch_bounds__(256)
void gemm_f16(const _Float16* __restrict__ Ap,   // [16][1024][1120]  (N side)
              const _Float16* __restrict__ Bp,   // [16][256][1120]   (M side)
              const float* __restrict__ orix,
              const float* __restrict__ alphap,
              float* __restrict__ out) {
    __shared__ __align__(16) _Float16 Am[64 * 32];    // channel tile
    __shared__ __align__(16) _Float16 Bn[128 * 32];   // pixel tile

    const int bc = blockIdx.z;
    const int b = bc >> 2, cls = bc & 3;
    const int ph = cls >> 1, pw = cls & 1;
    const int c0 = blockIdx.x * 64;       // gridDim.x = 4
    const int px0 = blockIdx.y * 128;     // gridDim.y = 8

    const int t = threadIdx.x;
    const int wv = t >> 6, l = t & 63;
    const int lr = l & 15, lk = l >> 4;

    const _Float16* Ag = Bp + ((size_t)bc * CC + c0) * KDIM;     // M operand
    const _Float16* Bg = Ap + ((size_t)bc * MROWS + px0) * KDIM; // N operand

    f32x4 acc[4][2];
    #pragma unroll
    for (int i = 0; i < 4; ++i)
        #pragma unroll
        for (int j = 0; j < 2; ++j)
            acc[i][j] = (f32x4){0.f, 0.f, 0.f, 0.f};

    for (int k0 = 0; k0 < KDIM; k0 += 32) {
        // stage channel tile: 64 rows x 32 k = 2048 halves (8/thread)
        {
            int u = t;
            *reinterpret_cast<f16x8*>(&Am[u * 8]) =
                *reinterpret_cast<const f16x8*>(
                    Ag + (size_t)(u >> 2) * KDIM + k0 + (u & 3) * 8);
        }
        // stage pixel tile: 128 rows x 32 k = 4096 halves (16/thread)
        #pragma unroll
        for (int r = 0; r < 2; ++r) {
            int u = r * 256 + t;
            *reinterpret_cast<f16x8*>(&Bn[u * 8]) =
                *reinterpret_cast<const f16x8*>(
                    Bg + (size_t)(u >> 2) * KDIM + k0 + (u & 3) * 8);
        }
        __syncthreads();

        f16x8 a[4], bf[2];
        #pragma unroll
        for (int m = 0; m < 4; ++m)
            a[m] = *reinterpret_cast<const f16x8*>(
                &Am[(m * 16 + lr) * 32 + lk * 8]);
        #pragma unroll
        for (int n = 0; n < 2; ++n)
            bf[n] = *reinterpret_cast<const f16x8*>(
                &Bn[(wv * 32 + n * 16 + lr) * 32 + lk * 8]);
        #pragma unroll
        for (int m = 0; m < 4; ++m)
            #pragma unroll
            for (int n = 0; n < 2; ++n)
                acc[m][n] = __builtin_amdgcn_mfma_f32_16x16x32_f16(
                    a[m], bf[n], acc[m][n], 0, 0, 0);
        __syncthreads();
    }

    const float scale = 0.25f * alphap[0];
    #pragma unroll
    for (int m = 0; m < 4; ++m) {
        #pragma unroll
        for (int n = 0; n < 2; ++n) {
            #pragma unroll
            for (int r = 0; r < 4; ++r) {
                int c = c0 + m * 16 + lk * 4 + r;          // D row = M dim
                int rowg = px0 + wv * 32 + n * 16 + lr;    // D col = N dim
                int hh = rowg >> 5, ww2 = rowg & 31;
                int h = 2 * hh + ph, wp = 2 * ww2 + pw;
                size_t idx = (((size_t)b * CC + c) * HH + h) * WW + wp;
                out[idx] = orix[idx] + scale * acc[m][n][r];
            }
        }
    }
}

// ===========================================================================
// FALLBACK PATH (round-1 kernels, used only if ws too small)
// ===========================================================================
#define TILE_M 64
#define TILE_N 64
#define TILE_K 16

__global__ void copy_kernel(const float* __restrict__ src,
                            float* __restrict__ dst, int n4) {
    int i = blockIdx.x * blockDim.x + threadIdx.x;
    if (i < n4)
        reinterpret_cast<float4*>(dst)[i] =
            reinterpret_cast<const float4*>(src)[i];
}

__global__ void transpose_kernel(const float* __restrict__ x,
                                 float* __restrict__ xT) {
    __shared__ float tile[32][33];
    int bh = blockIdx.z;
    int b = bh >> 6, h = bh & 63;
    int c0 = blockIdx.y * 32, w0 = blockIdx.x * 32;
    int tw = threadIdx.x & 31;
    int tc = threadIdx.x >> 5;
    #pragma unroll
    for (int i = 0; i < 4; ++i) {
        int c = tc + i * 8;
        tile[c][tw] = x[(((size_t)b * CC + c0 + c) * HH + h) * WW + w0 + tw];
    }
    __syncthreads();
    int tcw = threadIdx.x & 31;
    int twr = threadIdx.x >> 5;
    #pragma unroll
    for (int i = 0; i < 4; ++i) {
        int w = twr + i * 8;
        xT[(((size_t)b * HH + h) * WW + w0 + w) * CC + c0 + tcw] = tile[tcw][w];
    }
}

__global__ __launch_bounds__(256)
void pgemm_scatter(const float* __restrict__ scores,
                   const float* __restrict__ xT,
                   const float* __restrict__ x,
                   const float* __restrict__ alpha,
                   float* __restrict__ out,
                   int use_xt) {
    __shared__ float As[TILE_K][TILE_M];
    __shared__ float Bs[TILE_K][TILE_N];

    const int b      = blockIdx.z;
    const int tile_n = blockIdx.x;
    const int m0     = blockIdx.y * TILE_M;
    const int uv     = tile_n >> 2;
    const int u      = uv >> 2, v = uv & 3;
    const int c0     = (tile_n & 3) * 64;

    const int t  = threadIdx.x;
    const int tx = t & 15;
    const int ty = t >> 4;

    float acc[4][4] = {};
    const float* sb = scores + (size_t)b * QRN * KN;

    for (int k0 = 0; k0 < KN; k0 += TILE_K) {
        {
            int mr = t >> 2;
            int kc = (t & 3) * 4;
            float4 av = *reinterpret_cast<const float4*>(
                sb + (size_t)(m0 + mr) * KN + k0 + kc);
            As[kc + 0][mr] = av.x;
            As[kc + 1][mr] = av.y;
            As[kc + 2][mr] = av.z;
            As[kc + 3][mr] = av.w;
        }
        {
            int kr = t >> 4;
            int kg = k0 + kr;
            int m  = kg >> 5, n = kg & 31;
            int rr = 2 * m + u - 1; rr = min(max(rr, 0), HH - 1);
            int cc = 2 * n + v - 1; cc = min(max(cc, 0), WW - 1);
            int ccol = (t & 15) * 4;
            if (use_xt) {
                float4 bv = *reinterpret_cast<const float4*>(
                    xT + ((((size_t)b * HH + rr) * WW + cc) * CC) + c0 + ccol);
                Bs[kr][ccol + 0] = bv.x;
                Bs[kr][ccol + 1] = bv.y;
                Bs[kr][ccol + 2] = bv.z;
                Bs[kr][ccol + 3] = bv.w;
            } else {
                #pragma unroll
                for (int j = 0; j < 4; ++j) {
                    int c = c0 + ccol + j;
                    Bs[kr][ccol + j] =
                        x[(((size_t)b * CC + c) * HH + rr) * WW + cc];
                }
            }
        }
        __syncthreads();

        #pragma unroll
        for (int k = 0; k < TILE_K; ++k) {
            float a4[4], b4[4];
            *reinterpret_cast<float4*>(a4) =
                *reinterpret_cast<const float4*>(&As[k][ty * 4]);
            *reinterpret_cast<float4*>(b4) =
                *reinterpret_cast<const float4*>(&Bs[k][tx * 4]);
            #pragma unroll
            for (int i = 0; i < 4; ++i)
                #pragma unroll
                for (int j = 0; j < 4; ++j)
                    acc[i][j] += a4[i] * b4[j];
        }
        __syncthreads();
    }

    const float scale = alpha[0] * 0.25f;
    #pragma unroll
    for (int i = 0; i < 4; ++i) {
        int qr = m0 + ty * 4 + i;
        int Q = qr >> 5, R = qr & 31;
        int h = 2 * Q + u - 1;
        int w = 2 * R + v - 1;
        if (h < 0 || h >= HH || w < 0 || w >= WW) continue;
        #pragma unroll
        for (int j = 0; j < 4; ++j) {
            int c = c0 + tx * 4 + j;
            atomicAdd(&out[(((size_t)b * CC + c) * HH + h) * WW + w],
                      acc[i][j] * scale);
        }
    }
}

// ===========================================================================
extern "C" void kernel_launch(void* const* d_in, const int* in_sizes, int n_in,
                              void* d_out, int out_size, void* d_ws,
                              size_t ws_size, hipStream_t stream) {
    const float* ori_x  = (const float*)d_in[0];
    const float* scores = (const float*)d_in[1];
    const float* alpha  = (const float*)d_in[2];
    float* out = (float*)d_out;

    const size_t need_fast = (AP_ELEMS + BP_ELEMS) * sizeof(_Float16);

    if (ws_size >= need_fast) {
        _Float16* Ap = (_Float16*)d_ws;
        _Float16* Bp = Ap + AP_ELEMS;

        build_A<<<dim3(5, 16 * MROWS), 256, 0, stream>>>(scores, Ap);
        build_B<<<dim3(5, 16 * CC), 256, 0, stream>>>(ori_x, Bp);
        gemm_f16<<<dim3(4, 8, 16), 256, 0, stream>>>(Ap, Bp, ori_x, alpha, out);
    } else {
        float* xT = (float*)d_ws;
        const size_t xt_bytes = (size_t)BB * HH * WW * CC * sizeof(float);
        const int use_xt = (ws_size >= xt_bytes) ? 1 : 0;

        copy_kernel<<<(BB * CC * HH * WW / 4 + 255) / 256, 256, 0, stream>>>(
            ori_x, out, BB * CC * HH * WW / 4);
        if (use_xt)
            transpose_kernel<<<dim3(WW / 32, CC / 32, BB * HH), 256, 0,
                               stream>>>(ori_x, xT);
        pgemm_scatter<<<dim3(NN / TILE_N, QRN / TILE_M, BB), 256, 0, stream>>>(
            scores, xT, ori_x, alpha, out, use_xt);
    }
}